// Round 1
// 1024.224 us; speedup vs baseline: 1.0662x; 1.0662x over previous
//
#include <hip/hip_runtime.h>
#include <stdint.h>

// Product2Vec on MI355X (gfx950). B=2048, N=128, D=512, HID=2048, H=8, DH=64.
// Runtime-adaptive input dtype (bf16 vs fp32) via device-side sniffer.
//
// Math restructure (single-query MHA):
//   qt[b,h,d]   = sum_e q'[b,h*64+e] * Wk[d, h*64+e],  q' = (emb@Wq+bq)/8
//   scores      = nb . qt      (q.bk shift is softmax-invariant -> dropped)
//   ctxraw[b,h] = attn @ nb[b]
//   ctx[b,h*64+j] = ctxraw[b,h,:] @ Wv[:, h*64+j] + bv   (sum attn = 1)
//   out = ctx @ Wo + bo
//
// R1 change: fused attention kernel (scores+softmax+PV) with the full
// 128x512 neighbor tile resident in LDS as bf16 -> neighbors read from HBM
// ONCE instead of twice (-536 MB). Launch count 28 -> 15 via segmented
// multi-copy / multi-transpose prep kernels.

typedef unsigned short u16;
typedef unsigned int u32;
typedef __attribute__((ext_vector_type(8))) short bf16x8;   // 8 bf16 (4 VGPRs)
typedef __attribute__((ext_vector_type(4))) float f32x4;

__device__ __forceinline__ float b2f(u16 h){
  union { u32 u; float f; } c; c.u = ((u32)h) << 16; return c.f;
}
__device__ __forceinline__ u16 f2b(float f){
  union { float f; u32 u; } c; c.f = f;
  u32 r = (c.u + 0x7fffu + ((c.u >> 16) & 1u)) >> 16;
  return (u16)r;
}
__device__ __forceinline__ float fast_tanh(float x){
  float ax = fabsf(x);
  float e  = __expf(2.0f * ax);
  float t  = 1.0f - 2.0f / (e + 1.0f);
  return x < 0.0f ? -t : t;
}
__device__ __forceinline__ void gl_lds16(const u16* g, u16* l){
  __builtin_amdgcn_global_load_lds((const __attribute__((address_space(1))) void*)g,
                                   (__attribute__((address_space(3))) void*)l,
                                   16, 0, 0);
}
__device__ __forceinline__ bool isf32(const int* flg){ return *flg > 32; }

// ------------- dtype sniffer: fp32 read as u16 -> ~12.5% exp>=0xC0; bf16 -> 0
__global__ void detect_kernel(const u16* w, int* flag){
  __shared__ int cnt[256];
  int c = 0;
  #pragma unroll
  for (int i = 0; i < 16; ++i){
    u16 v = w[threadIdx.x * 16 + i];
    if (((v >> 7) & 0xff) >= 0xC0) c++;
  }
  cnt[threadIdx.x] = c;
  __syncthreads();
  if (threadIdx.x == 0){
    int s = 0;
    for (int i = 0; i < 256; ++i) s += cnt[i];
    *flag = s;
  }
}

// ------------- adaptive segmented copy to bf16 (4 elems/thread, 10 segments)
struct CopyArgs {
  const void* src[10];
  u16* dst[10];
  int end[10];       // exclusive prefix-sum of 4-elem groups
};

__global__ __launch_bounds__(256) void conv_copy_multi(
    CopyArgs a, int total, const int* __restrict__ flg)
{
  int g = blockIdx.x * 256 + threadIdx.x;
  if (g >= total) return;
  // compile-time-unrolled segment select (no dynamic struct indexing -> no scratch)
  const void* sp = a.src[0]; u16* dp = a.dst[0]; int base = 0;
  #pragma unroll
  for (int k = 1; k < 10; ++k){
    if (g >= a.end[k-1]){ sp = a.src[k]; dp = a.dst[k]; base = a.end[k-1]; }
  }
  int i = g - base;
  if (isf32(flg)){
    float4 v = ((const float4*)sp)[i];
    ushort4 o; o.x = f2b(v.x); o.y = f2b(v.y); o.z = f2b(v.z); o.w = f2b(v.w);
    ((ushort4*)dp)[i] = o;
  } else {
    ((ushort4*)dp)[i] = ((const ushort4*)sp)[i];
  }
}

// ------------- adaptive segmented transpose to bf16: out[C][R] = in[R][C]
struct TpArgs {
  const void* src[6];
  u16* dst[6];
  int R[6];
  int C[6];
  int tX[6];         // column tiles = C/32
  int start[6];      // first flat block id of each segment
};

__global__ __launch_bounds__(256) void conv_transpose_multi(
    TpArgs a, const int* __restrict__ flg)
{
  __shared__ u16 t[32][33];
  const int bid = blockIdx.x;
  const void* in = a.src[0]; u16* out = a.dst[0];
  int R = a.R[0], Cc = a.C[0], tX = a.tX[0], base = 0;
  #pragma unroll
  for (int k = 1; k < 6; ++k){
    if (bid >= a.start[k]){
      in = a.src[k]; out = a.dst[k];
      R = a.R[k]; Cc = a.C[k]; tX = a.tX[k]; base = a.start[k];
    }
  }
  int lid = bid - base;
  int c0 = (lid % tX) * 32, r0 = (lid / tX) * 32;
  int lr = threadIdx.x >> 5, lc = threadIdx.x & 31;
  bool f = isf32(flg);
  #pragma unroll
  for (int p = 0; p < 4; ++p){
    int r = p * 8 + lr;
    size_t idx = (size_t)(r0 + r) * Cc + c0 + lc;
    t[r][lc] = f ? f2b(((const float*)in)[idx]) : ((const u16*)in)[idx];
  }
  __syncthreads();
  #pragma unroll
  for (int p = 0; p < 4; ++p){
    int c = p * 8 + lr;
    out[(size_t)(c0 + c) * R + r0 + lc] = t[lc][c];
  }
}

// ---------------- bf16 GEMM: C = epi(A @ Bt^T + bias) ----------------
// A [M][lda] (k contig), Bt [N][ldb] (k contig), C [M][ldc]. 128 x (NT*32) tile,
// BK=32, 256 thr = 4 waves (2x2). epi: 0=+bias, 1=tanh, 2=*0.125. outflg: f32 C.
template<int NT>
__global__ __launch_bounds__(256) void gemm_bt(
    const u16* __restrict__ A, int lda,
    const u16* __restrict__ Bt, int ldb,
    u16* __restrict__ C, int ldc,
    const u16* __restrict__ bias,
    int K, int epi,
    int aOffZ, int bOffZ, int cOffZ, int biasOffZ,
    const int* outflg)
{
  constexpr int BN2 = NT * 16;
  __shared__ u16 As[128 * 32];
  __shared__ u16 Bs[NT * 32 * 32];
  const int z = blockIdx.z;
  A  += (size_t)z * aOffZ;
  Bt += (size_t)z * bOffZ;
  C  += (size_t)z * cOffZ;
  if (bias) bias += z * biasOffZ;

  const int tid = threadIdx.x;
  const int w = tid >> 6, l = tid & 63;
  const int wm = w & 1, wn = w >> 1;
  const int m0 = blockIdx.x * 128;
  const int n0 = blockIdx.y * (NT * 32);
  const int l15 = l & 15;
  const int kq  = (l >> 4) * 8;

  f32x4 acc[4][NT];
  #pragma unroll
  for (int i = 0; i < 4; ++i)
    #pragma unroll
    for (int j = 0; j < NT; ++j)
      acc[i][j] = (f32x4){0.f, 0.f, 0.f, 0.f};

  const int nkt = K >> 5;
  for (int kt = 0; kt < nkt; ++kt){
    const int k0 = kt << 5;
    __syncthreads();
    #pragma unroll
    for (int it = 0; it < 2; ++it){
      int e = (it * 4 + w) * 512 + l * 8;
      gl_lds16(A + (size_t)(m0 + (e >> 5)) * lda + k0 + (e & 31), &As[e]);
    }
    #pragma unroll
    for (int it = 0; it < NT / 2; ++it){
      int e = (it * 4 + w) * 512 + l * 8;
      gl_lds16(Bt + (size_t)(n0 + (e >> 5)) * ldb + k0 + (e & 31), &Bs[e]);
    }
    __syncthreads();
    bf16x8 af[4], bfr[NT];
    #pragma unroll
    for (int mt = 0; mt < 4; ++mt)
      af[mt] = *(const bf16x8*)&As[(wm * 64 + mt * 16 + l15) * 32 + kq];
    #pragma unroll
    for (int nt = 0; nt < NT; ++nt)
      bfr[nt] = *(const bf16x8*)&Bs[(wn * BN2 + nt * 16 + l15) * 32 + kq];
    #pragma unroll
    for (int mt = 0; mt < 4; ++mt)
      #pragma unroll
      for (int nt = 0; nt < NT; ++nt)
        acc[mt][nt] = __builtin_amdgcn_mfma_f32_16x16x32_bf16(af[mt], bfr[nt], acc[mt][nt], 0, 0, 0);
  }

  const bool f32o = outflg && isf32(outflg);
  const int q4 = (l >> 4) * 4;
  #pragma unroll
  for (int nt = 0; nt < NT; ++nt){
    int n = n0 + wn * BN2 + nt * 16 + l15;
    float bb = bias ? b2f(bias[n]) : 0.0f;
    #pragma unroll
    for (int mt = 0; mt < 4; ++mt){
      #pragma unroll
      for (int r = 0; r < 4; ++r){
        int m = m0 + wm * 64 + mt * 16 + q4 + r;
        float x = acc[mt][nt][r] + bb;
        if (epi == 1) x = fast_tanh(x);
        else if (epi == 2) x *= 0.125f;
        if (f32o) ((float*)C)[(size_t)m * ldc + n] = x;
        else      C[(size_t)m * ldc + n] = f2b(x);
      }
    }
  }
}

// ---------------- BatchNorm over B=2048 rows of X[2048][2048] ----------------
__global__ __launch_bounds__(256) void bn_stats(
    const u16* __restrict__ X, float* __restrict__ s1, float* __restrict__ s2)
{
  int c  = blockIdx.x * 256 + threadIdx.x;
  int r0 = blockIdx.y * 256;
  float a = 0.f, b = 0.f;
  for (int r = 0; r < 256; ++r){
    float x = b2f(X[(size_t)(r0 + r) * 2048 + c]);
    a += x; b += x * x;
  }
  atomicAdd(&s1[c], a);
  atomicAdd(&s2[c], b);
}

__global__ __launch_bounds__(256) void bn_fin(
    const float* __restrict__ s1, const float* __restrict__ s2,
    const u16* __restrict__ gamma, const u16* __restrict__ beta,
    float* __restrict__ A, float* __restrict__ Cc)
{
  int j = blockIdx.x * 256 + threadIdx.x;
  float mu  = s1[j] * (1.0f / 2048.0f);
  float var = s2[j] * (1.0f / 2048.0f) - mu * mu;
  float a = b2f(gamma[j]) * rsqrtf(var + 1e-5f);
  A[j]  = a;
  Cc[j] = b2f(beta[j]) - mu * a;
}

__global__ __launch_bounds__(256) void bn_apply(
    u16* __restrict__ X, const float* __restrict__ A, const float* __restrict__ Cc)
{
  int i = blockIdx.x * 256 + threadIdx.x;
  uint4 v = ((const uint4*)X)[i];
  u16* p = (u16*)&v;
  int base = i * 8;
  #pragma unroll
  for (int e = 0; e < 8; ++e){
    int j = (base + e) & 2047;
    p[e] = f2b(A[j] * b2f(p[e]) + Cc[j]);
  }
  ((uint4*)X)[i] = v;
}

// ---------------- fused attention: scores + softmax + PV, nb staged ONCE ----
// 2048 blocks x 512 thr (8 waves), 1 block/CU.
// LDS: nbS 128x520 bf16 (133.1KB) + qtS 16x520 bf16 (16.6KB)
//      + scS 128x9 f32 (4.6KB) + atT 128x8 f32 (4KB) = 154.75 KB (<160KB).
// Phases: stage(fp32->bf16) -> QK^T MFMA (wave w owns n-rows [16w,16w+16))
//         -> softmax (wave w owns head w) -> VALU PV (4 waves, d-pair/thread).
// NOTE: ctxr_g aliases qt_g per block b (read staged before write; per-block
// regions disjoint across blocks) -- safe.
__global__ __launch_bounds__(512) void att_fused(
    const void* __restrict__ nb_g, const int* __restrict__ lengths,
    const u16* __restrict__ qt_g, u16* __restrict__ ctxr_g, const int* flg)
{
  __shared__ u16 nbS[128 * 520];
  __shared__ u16 qtS[16 * 520];
  __shared__ float scS[128 * 9];
  __shared__ float atT[128 * 8];
  const int b = blockIdx.x, tid = threadIdx.x;
  const int w = tid >> 6, l = tid & 63;
  const int l15 = l & 15, kq = (l >> 4) * 8;
  const bool f = isf32(flg);

  // ---- stage qt: 8 real rows + 8 zero rows (MFMA B-operand padding)
  {
    int i = tid * 8;                      // 0..4088 over 8x512
    int row = i >> 9, col = i & 511;
    *(uint4*)&qtS[row * 520 + col] = *(const uint4*)&qt_g[(size_t)b * 4096 + i];
    uint4 zz; zz.x = zz.y = zz.z = zz.w = 0u;
    *(uint4*)&qtS[(8 + row) * 520 + col] = zz;
  }
  // ---- stage neighbors 128x512 -> bf16 LDS (fp32 converted in flight)
  #pragma unroll
  for (int it = 0; it < 16; ++it){
    int c = (it * 512 + tid) * 8;
    int row = c >> 9, col = c & 511;
    size_t base = (size_t)b * 65536 + c;
    uint4 v;
    if (f){
      float4 a  = *(const float4*)((const float*)nb_g + base);
      float4 bb = *(const float4*)((const float*)nb_g + base + 4);
      u16* p = (u16*)&v;
      p[0]=f2b(a.x); p[1]=f2b(a.y); p[2]=f2b(a.z); p[3]=f2b(a.w);
      p[4]=f2b(bb.x);p[5]=f2b(bb.y);p[6]=f2b(bb.z);p[7]=f2b(bb.w);
    } else {
      v = *(const uint4*)((const u16*)nb_g + base);
    }
    *(uint4*)&nbS[row * 520 + col] = v;
  }
  __syncthreads();

  // ---- QK^T: wave w owns neighbor rows [w*16, w*16+16), all 512 k
  {
    f32x4 acc = (f32x4){0.f, 0.f, 0.f, 0.f};
    const int n = w * 16 + l15;
    #pragma unroll
    for (int ks = 0; ks < 16; ++ks){
      bf16x8 a  = *(const bf16x8*)&nbS[n * 520 + ks * 32 + kq];
      bf16x8 q8 = *(const bf16x8*)&qtS[l15 * 520 + ks * 32 + kq];
      acc = __builtin_amdgcn_mfma_f32_16x16x32_bf16(a, q8, acc, 0, 0, 0);
    }
    const int q4 = (l >> 4) * 4;
    if (l15 < 8){
      #pragma unroll
      for (int r = 0; r < 4; ++r)
        scS[(w * 16 + q4 + r) * 9 + l15] = acc[r];
    }
  }
  __syncthreads();

  // ---- softmax: wave w handles head h=w; lane l holds n=l and n=64+l
  {
    const int len = lengths[b];
    const int h = w;
    float s0 = scS[l * 9 + h], s1 = scS[(64 + l) * 9 + h];
    float m0 = (l < len)      ? s0 : -3.0e38f;
    float m1 = (64 + l < len) ? s1 : -3.0e38f;
    float m = fmaxf(m0, m1);
    #pragma unroll
    for (int o = 32; o > 0; o >>= 1) m = fmaxf(m, __shfl_xor(m, o, 64));
    float e0 = (l < len)      ? __expf(s0 - m) : 0.0f;
    float e1 = (64 + l < len) ? __expf(s1 - m) : 0.0f;
    float s = e0 + e1;
    #pragma unroll
    for (int o = 32; o > 0; o >>= 1) s += __shfl_xor(s, o, 64);
    float inv = 1.0f / s;
    atT[l * 8 + h]        = e0 * inv;   // [n][h], f32 (no bf16 round trip)
    atT[(64 + l) * 8 + h] = e1 * inv;
  }
  __syncthreads();

  // ---- PV: first 4 waves; thread owns d-pair (2*tid, 2*tid+1)
  if (tid < 256){
    float a0[8], a1[8];
    #pragma unroll
    for (int h = 0; h < 8; ++h){ a0[h] = 0.f; a1[h] = 0.f; }
    #pragma unroll 4
    for (int n = 0; n < 128; ++n){
      u32 vv = *(const u32*)&nbS[n * 520 + tid * 2];
      union { u32 u; float f; } c0, c1;
      c0.u = vv << 16;
      c1.u = vv & 0xffff0000u;
      float4 p0 = *(const float4*)&atT[n * 8];
      float4 p1 = *(const float4*)&atT[n * 8 + 4];
      a0[0] += p0.x * c0.f; a1[0] += p0.x * c1.f;
      a0[1] += p0.y * c0.f; a1[1] += p0.y * c1.f;
      a0[2] += p0.z * c0.f; a1[2] += p0.z * c1.f;
      a0[3] += p0.w * c0.f; a1[3] += p0.w * c1.f;
      a0[4] += p1.x * c0.f; a1[4] += p1.x * c1.f;
      a0[5] += p1.y * c0.f; a1[5] += p1.y * c1.f;
      a0[6] += p1.z * c0.f; a1[6] += p1.z * c1.f;
      a0[7] += p1.w * c0.f; a1[7] += p1.w * c1.f;
    }
    #pragma unroll
    for (int h = 0; h < 8; ++h){
      u32 o = (u32)f2b(a0[h]) | ((u32)f2b(a1[h]) << 16);
      ((u32*)ctxr_g)[(size_t)b * 2048 + h * 256 + tid] = o;
    }
  }
}

// ---------------- host ----------------
extern "C" void kernel_launch(void* const* d_in, const int* in_sizes, int n_in,
                              void* d_out, int out_size, void* d_ws, size_t ws_size,
                              hipStream_t stream)
{
  (void)in_sizes; (void)n_in; (void)out_size; (void)ws_size;
  const void* cat   = d_in[0];
  const void* nbg   = d_in[1];
  const int*  len   = (const int*)d_in[2];
  const void* W1    = d_in[3];
  const void* b1    = d_in[4];
  const void* gamma = d_in[5];
  const void* beta  = d_in[6];
  const void* W2    = d_in[7];
  const void* b2    = d_in[8];
  const void* W3    = d_in[9];
  const void* b3    = d_in[10];
  const void* Wq    = d_in[11];
  const void* bq    = d_in[12];
  const void* Wk    = d_in[13];
  // d_in[14] = bk: softmax-invariant score shift, unused
  const void* Wv    = d_in[15];
  const void* bv    = d_in[16];
  const void* Wo    = d_in[17];
  const void* bo    = d_in[18];

  char* ws = (char*)d_ws;
  u16* X1   = (u16*)(ws + 0);          // [2048][2048]; qt/ctxr alias [0,16MB)
  u16* X2   = (u16*)(ws + 8388608);
  u16* qt   = (u16*)(ws + 0);          // [2048][8][512] after X1/X2 dead
  u16* ctxr = qt;                      // fused att writes over qt per-block (safe)
  u16* emb  = (u16*)(ws + 16777216);   // [2048][512]
  u16* q    = (u16*)(ws + 18874368);   // [2048][512]
  u16* ctx  = (u16*)(ws + 20971520);   // [2048][512]
  u16* catB = (u16*)(ws + 27262976);   // [2048][512]
  u16* WkB  = (u16*)(ws + 29360128);   // [512][512]
  u16* W1T  = (u16*)(ws + 29884416);   // [2048][512]
  u16* W2T  = (u16*)(ws + 31981568);   // [2048][2048]
  u16* W3T  = (u16*)(ws + 40370176);   // [512][2048]
  u16* WqT  = (u16*)(ws + 42467328);   // [512][512]
  u16* WvT  = (u16*)(ws + 42991616);
  u16* WoT  = (u16*)(ws + 43515904);
  u16* bB   = (u16*)(ws + 44040192);   // b1,gamma,beta,b2 (2048 ea) b3,bq,bv,bo (512 ea)
  float* s1 = (float*)(ws + 44060672);
  float* s2 = (float*)(ws + 44068864);
  float* bnA= (float*)(ws + 44077056);
  float* bnC= (float*)(ws + 44085248);
  int* flag = (int*)(ws + 44093440);

  u16 *b1B = bB, *gmB = bB + 2048, *btB = bB + 4096, *b2B = bB + 6144;
  u16 *b3B = bB + 8192, *bqB = bB + 8704, *bvB = bB + 9216, *boB = bB + 9728;

  detect_kernel<<<1, 256, 0, stream>>>((const u16*)W1, flag);

  // ---- single segmented copy launch (cat, Wk, 8 bias vectors)
  {
    CopyArgs ca;
    const void* csrc[10] = {cat, Wk, b1, gamma, beta, b2, b3, bq, bv, bo};
    u16* cdst[10] = {catB, WkB, b1B, gmB, btB, b2B, b3B, bqB, bvB, boB};
    const int cnt[10] = {262144, 65536, 512, 512, 512, 512, 128, 128, 128, 128};
    int acc = 0;
    for (int i = 0; i < 10; ++i){
      ca.src[i] = csrc[i]; ca.dst[i] = cdst[i];
      acc += cnt[i]; ca.end[i] = acc;
    }
    conv_copy_multi<<<(acc + 255) / 256, 256, 0, stream>>>(ca, acc, flag);
  }

  // ---- single segmented transpose launch (W1,W2,W3,Wq,Wv,Wo)
  {
    TpArgs ta;
    const void* tsrc[6] = {W1, W2, W3, Wq, Wv, Wo};
    u16* tdst[6] = {W1T, W2T, W3T, WqT, WvT, WoT};
    const int tR[6] = {512, 2048, 2048, 512, 512, 512};
    const int tC[6] = {2048, 2048, 512, 512, 512, 512};
    int s = 0;
    for (int i = 0; i < 6; ++i){
      ta.src[i] = tsrc[i]; ta.dst[i] = tdst[i];
      ta.R[i] = tR[i]; ta.C[i] = tC[i]; ta.tX[i] = tC[i] / 32;
      ta.start[i] = s;
      s += (tC[i] / 32) * (tR[i] / 32);
    }
    conv_transpose_multi<<<s, 256, 0, stream>>>(ta, flag);   // s = 6912
  }

  hipMemsetAsync(s1, 0, 16384, stream);  // s1 + s2

  // FFN
  gemm_bt<4><<<dim3(16, 16), 256, 0, stream>>>(catB, 512, W1T, 512, X1, 2048, b1B, 512, 1, 0, 0, 0, 0, nullptr);
  bn_stats<<<dim3(8, 8), 256, 0, stream>>>(X1, s1, s2);
  bn_fin  <<<8, 256, 0, stream>>>(s1, s2, gmB, btB, bnA, bnC);
  bn_apply<<<2048, 256, 0, stream>>>(X1, bnA, bnC);
  gemm_bt<4><<<dim3(16, 16), 256, 0, stream>>>(X1, 2048, W2T, 2048, X2, 2048, b2B, 2048, 1, 0, 0, 0, 0, nullptr);
  gemm_bt<4><<<dim3(16, 4), 256, 0, stream>>>(X2, 2048, W3T, 2048, emb, 512, b3B, 2048, 0, 0, 0, 0, 0, nullptr);

  // q' = (emb@Wq + bq)/8 ; qt[b,h,:] = q'[b,h-slice] @ Wk[:,h-slice]^T (grid.z = head)
  gemm_bt<4><<<dim3(16, 4), 256, 0, stream>>>(emb, 512, WqT, 512, q, 512, bqB, 512, 2, 0, 0, 0, 0, nullptr);
  gemm_bt<4><<<dim3(16, 4, 8), 256, 0, stream>>>(q, 512, WkB, 512, qt, 4096, nullptr, 64, 0, 64, 64, 512, 0, nullptr);

  // fused attention: neighbors streamed from HBM exactly once
  att_fused<<<2048, 512, 0, stream>>>(nbg, len, qt, ctxr, flag);

  // ctx[b, h-slice] = ctxraw[b,h,:] @ Wv[:, h-slice] + bv  (grid.z = head)
  gemm_bt<2><<<dim3(16, 1, 8), 256, 0, stream>>>(ctxr, 4096, WvT, 512, ctx, 512, bvB, 512, 0, 512, 32768, 64, 64, nullptr);

  // out = ctx @ Wo + bo (adaptive output dtype)
  gemm_bt<4><<<dim3(16, 4), 256, 0, stream>>>(ctx, 512, WoT, 512, (u16*)d_out, 512, boB, 512, 0, 0, 0, 0, 0, flag);
}